// Round 4
// baseline (176.184 us; speedup 1.0000x reference)
//
#include <hip/hip_runtime.h>
#include <hip/hip_bf16.h>

// ---------- types ----------
typedef float f32x4 __attribute__((ext_vector_type(4)));
typedef float f32x16 __attribute__((ext_vector_type(16)));
typedef __bf16 bf16x8 __attribute__((ext_vector_type(8)));

// fp32 -> bf16 RNE
__device__ __forceinline__ unsigned short f2bf(float f){
  unsigned int u = __builtin_bit_cast(unsigned int, f);
  u += 0x7fffu + ((u >> 16) & 1u);
  return (unsigned short)(u >> 16);
}
__device__ __forceinline__ float bf2f(unsigned short h){
  return __builtin_bit_cast(float, (unsigned int)h << 16);
}

__device__ __forceinline__ void glds16(const void* g, void* l){
  __builtin_amdgcn_global_load_lds((const __attribute__((address_space(1))) void*)g,
                                   (__attribute__((address_space(3))) void*)l, 16, 0, 0);
}

__device__ __forceinline__ f32x4 mfma16(bf16x8 a, bf16x8 b, f32x4 c){
  return __builtin_amdgcn_mfma_f32_16x16x32_bf16(a, b, c, 0, 0, 0);
}
__device__ __forceinline__ f32x16 mfma32(bf16x8 a, bf16x8 b, f32x16 c){
  return __builtin_amdgcn_mfma_f32_32x32x16_bf16(a, b, c, 0, 0, 0);
}

#if __has_builtin(__builtin_amdgcn_exp2f)
__device__ __forceinline__ float exp2v(float x){ return __builtin_amdgcn_exp2f(x); }
#else
__device__ __forceinline__ float exp2v(float x){ return exp2f(x); }
#endif

// packed f32x2 -> bf16x2 (gfx950)
__device__ __forceinline__ unsigned int cvtpk(float a, float b){
  unsigned int r;
  asm("v_cvt_pk_bf16_f32 %0, %1, %2" : "=v"(r) : "v"(a), "v"(b));
  return r;
}

// ---------- kernel: detect mask dtype (bool-bytes vs int32) ----------
__global__ void detect_kernel(const unsigned int* __restrict__ m, int* __restrict__ flag){
  int t = threadIdx.x;
  int bad = 0;
  for(int i = t; i < 4096; i += 256) bad |= (m[i] > 1u);
  unsigned long long b = __ballot(bad != 0);
  __shared__ int sbuf[4];
  if((t & 63) == 0) sbuf[t >> 6] = (b != 0ull);
  __syncthreads();
  if(t == 0) flag[0] = (sbuf[0] | sbuf[1] | sbuf[2] | sbuf[3]) ? 0 : 1; // 1 => int32
}

// ---------- kernel: pack mask into bits (mp[row][64 words]) ----------
__global__ void pack_mask_kernel(const unsigned char* __restrict__ m8,
                                 unsigned int* __restrict__ mp,
                                 const int* __restrict__ flag){
  const int wid = threadIdx.x >> 6, lane = threadIdx.x & 63;
  const int row = blockIdx.x * 4 + wid;            // 0..4095 (b*2048+q)
  const int is32 = flag[0];
  const int* m32 = (const int*)m8;
  for(int c0 = 0; c0 < 2048; c0 += 64){
    int mv = is32 ? m32[(size_t)row*2048 + c0 + lane]
                  : (int)m8[(size_t)row*2048 + c0 + lane];
    unsigned long long b = __ballot(mv != 0);
    if(lane == 0){
      mp[(size_t)row*64 + (c0 >> 5)]     = (unsigned int)b;
      mp[(size_t)row*64 + (c0 >> 5) + 1] = (unsigned int)(b >> 32);
    }
  }
}

// ---------- kernel: fp32 -> bf16 convert ----------
__global__ void cvt_kernel(const float* __restrict__ src, unsigned short* __restrict__ dst){
  int i = blockIdx.x * 256 + threadIdx.x;
  const float4* s = (const float4*)src;
  float4 a = s[2*i], b = s[2*i+1];
  union { unsigned short h[8]; uint4 v; } o;
  o.h[0]=f2bf(a.x); o.h[1]=f2bf(a.y); o.h[2]=f2bf(a.z); o.h[3]=f2bf(a.w);
  o.h[4]=f2bf(b.x); o.h[5]=f2bf(b.y); o.h[6]=f2bf(b.z); o.h[7]=f2bf(b.w);
  ((uint4*)dst)[i] = o.v;
}

// ---------- kernel: W[1024][1024] f32 -> W^T bf16 ----------
__global__ void transW_kernel(const float* __restrict__ Wq, const float* __restrict__ Wk,
                              const float* __restrict__ Wv, const float* __restrict__ Wo,
                              unsigned short* __restrict__ WT){
  const float* W = (blockIdx.y==0)?Wq:(blockIdx.y==1)?Wk:(blockIdx.y==2)?Wv:Wo;
  unsigned short* D = WT + (size_t)blockIdx.y * 1048576;
  int r0 = (blockIdx.x >> 4) * 64, c0 = (blockIdx.x & 15) * 64;
  __shared__ unsigned short T[64][65];
  int t = threadIdx.x;
  {
    int r = t >> 2, cb = (t & 3) * 16;
    const float4* src = (const float4*)(W + (size_t)(r0 + r) * 1024 + (c0 + cb));
    float4 v0 = src[0], v1 = src[1], v2 = src[2], v3 = src[3];
    float vals[16] = {v0.x,v0.y,v0.z,v0.w, v1.x,v1.y,v1.z,v1.w,
                      v2.x,v2.y,v2.z,v2.w, v3.x,v3.y,v3.z,v3.w};
    #pragma unroll
    for(int j=0;j<16;j++) T[cb + j][r] = f2bf(vals[j]);
  }
  __syncthreads();
  {
    int c = t >> 2, rb = (t & 3) * 16;
    union { unsigned short h[16]; uint4 v[2]; } o;
    #pragma unroll
    for(int j=0;j<16;j++) o.h[j] = T[c][rb + j];
    uint4* dp = (uint4*)(D + (size_t)(c0 + c) * 1024 + (r0 + rb));
    dp[0] = o.v[0]; dp[1] = o.v[1];
  }
}

// ---------- kernel: per-head transpose Vb[token][1024] -> Vt[bh*64+d][2048] ----------
__global__ void transV_kernel(const unsigned short* __restrict__ Vb,
                              unsigned short* __restrict__ Vt){
  const int bh = blockIdx.y, b = bh >> 4, h = bh & 15;
  const int s0 = blockIdx.x * 64;
  __shared__ unsigned short T[64][68];
  const int t = threadIdx.x;
  {
    int r = t >> 2, cb = (t & 3) * 16;
    const uint4* src = (const uint4*)(Vb + (size_t)(b*2048 + s0 + r)*1024 + h*64 + cb);
    union { unsigned short h[16]; uint4 v[2]; } o;
    o.v[0] = src[0]; o.v[1] = src[1];
    uint2* dst = (uint2*)&T[r][cb];
    const uint2* sv = (const uint2*)o.h;
    dst[0]=sv[0]; dst[1]=sv[1]; dst[2]=sv[2]; dst[3]=sv[3];
  }
  __syncthreads();
  {
    int c = t >> 2, sb = (t & 3) * 16;
    union { unsigned short h[16]; uint4 v[2]; } o;
    #pragma unroll
    for(int j=0;j<16;j++) o.h[j] = T[sb + j][c];
    uint4* dp = (uint4*)(Vt + (size_t)(bh*64 + c)*2048 + s0 + sb);
    dp[0] = o.v[0]; dp[1] = o.v[1];
  }
}

// ---------- kernel: C[M=4096][N=1024] = A @ BT^T, bf16, 128x128 tile ----------
template<int OUTF32>
__global__ __launch_bounds__(256,2) void gemm_bt(
    const unsigned short* __restrict__ A0, const unsigned short* __restrict__ A1, const unsigned short* __restrict__ A2,
    const unsigned short* __restrict__ B0, const unsigned short* __restrict__ B1, const unsigned short* __restrict__ B2,
    unsigned short* __restrict__ C0, unsigned short* __restrict__ C1, unsigned short* __restrict__ C2,
    float* __restrict__ Cf)
{
  const unsigned short* A  = (blockIdx.z==0)?A0:(blockIdx.z==1)?A1:A2;
  const unsigned short* BT = (blockIdx.z==0)?B0:(blockIdx.z==1)?B1:B2;
  unsigned short* C        = (blockIdx.z==0)?C0:(blockIdx.z==1)?C1:C2;
  __shared__ unsigned short Asm[128*32];
  __shared__ unsigned short Bsm[128*32];
  const int wid = threadIdx.x >> 6, lane = threadIdx.x & 63;
  const int m0 = blockIdx.x * 128, n0 = blockIdx.y * 128;
  const int wrow = wid >> 1, wcol = wid & 1;
  f32x4 acc[4][4] = {};
  const int sr = lane >> 2;
  const int sc = lane & 3;

  for(int kt = 0; kt < 32; ++kt){
    const int kofs = kt * 32;
    #pragma unroll
    for(int i=0;i<2;i++){
      int r = wid*32 + i*16 + sr;
      int blk = sc ^ (r & 3);
      glds16(A  + (size_t)(m0 + r)*1024 + kofs + blk*8, &Asm[(wid*32 + i*16)*32]);
      glds16(BT + (size_t)(n0 + r)*1024 + kofs + blk*8, &Bsm[(wid*32 + i*16)*32]);
    }
    __syncthreads();
    bf16x8 af[4], bfv[4];
    #pragma unroll
    for(int fm=0; fm<4; fm++){
      int row = wrow*64 + fm*16 + (lane & 15);
      int blk = (lane >> 4) ^ (row & 3);
      af[fm] = *(const bf16x8*)&Asm[row*32 + blk*8];
    }
    #pragma unroll
    for(int fn=0; fn<4; fn++){
      int row = wcol*64 + fn*16 + (lane & 15);
      int blk = (lane >> 4) ^ (row & 3);
      bfv[fn] = *(const bf16x8*)&Bsm[row*32 + blk*8];
    }
    __builtin_amdgcn_s_setprio(1);
    #pragma unroll
    for(int fm=0; fm<4; fm++)
      #pragma unroll
      for(int fn=0; fn<4; fn++)
        acc[fm][fn] = mfma16(af[fm], bfv[fn], acc[fm][fn]);
    __builtin_amdgcn_s_setprio(0);
    __syncthreads();
  }
  #pragma unroll
  for(int fm=0; fm<4; fm++){
    #pragma unroll
    for(int fn=0; fn<4; fn++){
      int col  = n0 + wcol*64 + fn*16 + (lane & 15);
      int rowb = m0 + wrow*64 + fm*16 + (lane >> 4)*4;
      #pragma unroll
      for(int r=0;r<4;r++){
        if(OUTF32) Cf[(size_t)(rowb + r)*1024 + col] = acc[fm][fn][r];
        else       C [(size_t)(rowb + r)*1024 + col] = f2bf(acc[fm][fn][r]);
      }
    }
  }
}

// ---------- kernel: flash attention v4 (32x32 MFMA, P fully in registers) ----------
// grid 512 (swizzled -> 16 qtiles x 32 bh), 4 waves x 32 q-rows (QBLK=128), KVB=64.
// S^T = mfma32(K, Q): lane holds 32 S-values of q-row (lane&31);
// k(reg,hi) = 32*ktile + (r&3)+8*(r>>2)+4*hi.
__global__ __launch_bounds__(256,2) void attn32_kernel(
    const unsigned short* __restrict__ Q, const unsigned short* __restrict__ K,
    const unsigned short* __restrict__ Vt, unsigned short* __restrict__ O,
    const unsigned int* __restrict__ mp)
{
  __shared__ unsigned short Ksm[2][64*64];
  __shared__ unsigned short Vsm[2][64*64];
  __shared__ float scalw[4][32];
  const int wid = threadIdx.x >> 6, lane = threadIdx.x & 63;
  const int orig = blockIdx.x;
  const int wg = (orig & 7) * 64 + (orig >> 3);   // XCD swizzle (512 % 8 == 0)
  const int qt = wg & 15, bh = wg >> 4;
  const int b = bh >> 4, h = bh & 15;
  const int q0 = qt * 128;
  const int l31 = lane & 31, hi = lane >> 5, l7 = lane & 7;
  const int qrow = q0 + wid*32 + l31;             // this lane's q-row (tile-local)

  // Q B-fragments, pre-scaled by 0.125*log2(e): qf[s] covers dk = s*16 + hi*8 ..+7
  bf16x8 qf[4];
  {
    const unsigned short* qp = Q + (size_t)(b*2048 + qrow)*1024 + h*64 + hi*8;
    #pragma unroll
    for(int s=0;s<4;s++){
      union { unsigned short u[8]; bf16x8 v; } uu;
      uu.v = *(const bf16x8*)(qp + s*16);
      #pragma unroll
      for(int j=0;j<8;j++) uu.u[j] = f2bf(bf2f(uu.u[j]) * 0.1803368801111601f);
      qf[s] = uu.v;
    }
  }

  f32x16 o0 = {}, o1 = {};
  float mrow = -__builtin_inff();
  float lrow = 0.f;

  const int srow = lane >> 3;
  const int sblk = (lane & 7) ^ srow;             // source-side swizzle for staging
  const size_t mbase = (size_t)(b*2048 + qrow) * 64;

  // stage tile 0
  #pragma unroll
  for(int i=0;i<2;i++){
    int r = wid*16 + i*8 + srow;
    glds16(K  + (size_t)(b*2048 + r)*1024 + h*64 + sblk*8, &Ksm[0][(wid*16 + i*8)*64]);
    glds16(Vt + (size_t)(bh*64 + r)*2048 + sblk*8,         &Vsm[0][(wid*16 + i*8)*64]);
  }
  uint2 mw = *(const uint2*)&mp[mbase];
  uint2 mwn;
  __syncthreads();

  int buf = 0;
  for(int t = 0; t < 32; ++t){
    const int kv0 = t * 64;
    if(t < 31){
      #pragma unroll
      for(int i=0;i<2;i++){
        int r = wid*16 + i*8 + srow;
        glds16(K  + (size_t)(b*2048 + kv0 + 64 + r)*1024 + h*64 + sblk*8, &Ksm[buf^1][(wid*16 + i*8)*64]);
        glds16(Vt + (size_t)(bh*64 + r)*2048 + kv0 + 64 + sblk*8,         &Vsm[buf^1][(wid*16 + i*8)*64]);
      }
      mwn = *(const uint2*)&mp[mbase + (size_t)((kv0 + 64) >> 5)];
    }
    // S^T = mfma32(K, Q): s0 = ktile0 (k 0..31), s1 = ktile1 (k 32..63)
    f32x16 s0 = {}, s1 = {};
    __builtin_amdgcn_s_setprio(1);
    #pragma unroll
    for(int s=0;s<4;s++){
      int pos = (2*s + hi) ^ l7;
      bf16x8 k0 = *(const bf16x8*)&Ksm[buf][(l31)*64      + pos*8];
      bf16x8 k1 = *(const bf16x8*)&Ksm[buf][(32 + l31)*64 + pos*8];
      s0 = mfma32(k0, qf[s], s0);
      s1 = mfma32(k1, qf[s], s1);
    }
    __builtin_amdgcn_s_setprio(0);
    // mask (bit k of own q-row)
    {
      unsigned int base0 = mw.x >> (hi*4);
      unsigned int base1 = mw.y >> (hi*4);
      #pragma unroll
      for(int r=0;r<16;r++){
        const int sh = (r&3) + 8*(r>>2);
        s0[r] = ((base0 >> sh) & 1u) ? -1.0e9f : s0[r];
        s1[r] = ((base1 >> sh) & 1u) ? -1.0e9f : s1[r];
      }
    }
    // tile max: per-thread tree + exchange with partner half
    float tmax;
    {
      float a = fmaxf(s0[0], s1[0]);
      #pragma unroll
      for(int r=1;r<16;r++) a = fmaxf(a, fmaxf(s0[r], s1[r]));
      tmax = fmaxf(a, __shfl_xor(a, 32));
    }
    // defer-rescale (T13)
    if(__any(tmax > mrow + 8.f)){
      float mn = fmaxf(mrow, tmax);
      float scal = exp2v(mrow - mn);
      mrow = mn;
      lrow *= scal;
      if(hi == 0) scalw[wid][l31] = scal;
      asm volatile("s_waitcnt lgkmcnt(0)" ::: "memory");
      __builtin_amdgcn_sched_barrier(0);
      #pragma unroll
      for(int r=0;r<16;r++){
        float sr = scalw[wid][(r&3) + 8*(r>>2) + 4*hi];
        o0[r] *= sr; o1[r] *= sr;
      }
    }
    // exp2 + lane-partial sum (in place)
    {
      float rs = 0.f;
      #pragma unroll
      for(int r=0;r<16;r++){
        float e0 = exp2v(s0[r] - mrow);
        float e1 = exp2v(s1[r] - mrow);
        s0[r] = e0; s1[r] = e1;
        rs += e0 + e1;
      }
      lrow += rs;
    }
    // pack P into A-fragments (in-register, partner-half exchange via shfl_xor 32)
    bf16x8 pa[4];
    {
      #pragma unroll
      for(int tt=0; tt<2; tt++){
        const f32x16& e = tt ? s1 : s0;
        #pragma unroll
        for(int u=0; u<2; u++){
          unsigned int y01 = cvtpk(e[u*8+0], e[u*8+1]);
          unsigned int y23 = cvtpk(e[u*8+2], e[u*8+3]);
          unsigned int y45 = cvtpk(e[u*8+4], e[u*8+5]);
          unsigned int y67 = cvtpk(e[u*8+6], e[u*8+7]);
          unsigned int t01 = __shfl_xor(y01, 32);
          unsigned int t23 = __shfl_xor(y23, 32);
          unsigned int t45 = __shfl_xor(y45, 32);
          unsigned int t67 = __shfl_xor(y67, 32);
          union { unsigned int w[4]; bf16x8 v; } fr;
          fr.w[0] = hi ? t45 : y01;
          fr.w[1] = hi ? t67 : y23;
          fr.w[2] = hi ? y45 : t01;
          fr.w[3] = hi ? y67 : t23;
          pa[tt*2 + u] = fr.v;
        }
      }
    }
    // O += P V
    __builtin_amdgcn_s_setprio(1);
    #pragma unroll
    for(int s=0;s<4;s++){
      int pos = (2*s + hi) ^ l7;
      bf16x8 v0 = *(const bf16x8*)&Vsm[buf][(l31)*64      + pos*8];
      bf16x8 v1 = *(const bf16x8*)&Vsm[buf][(32 + l31)*64 + pos*8];
      o0 = mfma32(pa[s], v0, o0);
      o1 = mfma32(pa[s], v1, o1);
    }
    __builtin_amdgcn_s_setprio(0);
    __syncthreads();
    mw = mwn;
    buf ^= 1;
  }
  // final normalization: row sum across partner halves, distribute inv to reg layout
  {
    float rs = lrow + __shfl_xor(lrow, 32);
    float inv = 1.0f / rs;
    if(hi == 0) scalw[wid][l31] = inv;
    asm volatile("s_waitcnt lgkmcnt(0)" ::: "memory");
    __builtin_amdgcn_sched_barrier(0);
    #pragma unroll
    for(int r=0;r<16;r++){
      const int qr = (r&3) + 8*(r>>2) + 4*hi;
      float iv = scalw[wid][qr];
      size_t row = (size_t)(b*2048 + q0 + wid*32 + qr);
      O[row*1024 + h*64 +      l31] = f2bf(o0[r] * iv);
      O[row*1024 + h*64 + 32 + l31] = f2bf(o1[r] * iv);
    }
  }
}

// ---------- launch ----------
extern "C" void kernel_launch(void* const* d_in, const int* in_sizes, int n_in,
                              void* d_out, int out_size, void* d_ws, size_t ws_size,
                              hipStream_t stream)
{
  const float* q_in = (const float*)d_in[0];
  const float* k_in = (const float*)d_in[1];
  const float* v_in = (const float*)d_in[2];
  const unsigned char* mask = (const unsigned char*)d_in[3];
  const float* Wq = (const float*)d_in[4];
  const float* Wk = (const float*)d_in[5];
  const float* Wv = (const float*)d_in[6];
  const float* Wo = (const float*)d_in[7];

  char* ws = (char*)d_ws;
  const size_t MB = 1024*1024;
  int* flag          = (int*)ws;                              // 256 B
  unsigned short* XQ = (unsigned short*)(ws + 256);           // 8 MB
  unsigned short* XK = (unsigned short*)(ws + 256 + 8*MB);    // 8 MB
  unsigned short* XV = (unsigned short*)(ws + 256 + 16*MB);   // 8 MB
  unsigned short* WT = (unsigned short*)(ws + 256 + 24*MB);   // 8 MB (4 matrices)
  unsigned short* Qb = (unsigned short*)(ws + 256 + 32*MB);   // 8 MB
  unsigned short* Kb = (unsigned short*)(ws + 256 + 40*MB);   // 8 MB
  unsigned short* Vb = (unsigned short*)(ws + 256 + 48*MB);   // 8 MB
  unsigned short* Ob = XQ;                                    // attention output
  unsigned short* Vt = XK;                                    // transposed V (8 MB)
  unsigned int*   mpk= (unsigned int*)XV;                     // packed mask (2 MB)

  detect_kernel<<<1, 256, 0, stream>>>((const unsigned int*)mask, flag);
  cvt_kernel<<<2048, 256, 0, stream>>>(q_in, XQ);
  cvt_kernel<<<2048, 256, 0, stream>>>(k_in, XK);
  cvt_kernel<<<2048, 256, 0, stream>>>(v_in, XV);
  transW_kernel<<<dim3(256,4), 256, 0, stream>>>(Wq, Wk, Wv, Wo, WT);
  gemm_bt<0><<<dim3(32,8,3), 256, 0, stream>>>(XQ, XK, XV,
                                               WT, WT + 1048576, WT + 2097152,
                                               Qb, Kb, Vb, nullptr);
  transV_kernel<<<dim3(32,32), 256, 0, stream>>>(Vb, Vt);
  pack_mask_kernel<<<1024, 256, 0, stream>>>(mask, mpk, flag);
  attn32_kernel<<<512, 256, 0, stream>>>(Qb, Kb, Vt, Ob, mpk);
  gemm_bt<1><<<dim3(32,8,1), 256, 0, stream>>>(Ob, Ob, Ob,
                                               WT + 3*1048576, WT + 3*1048576, WT + 3*1048576,
                                               nullptr, nullptr, nullptr, (float*)d_out);
}

// Round 5
// 161.661 us; speedup vs baseline: 1.0898x; 1.0898x over previous
//
#include <hip/hip_runtime.h>
#include <hip/hip_bf16.h>

// ---------- types ----------
typedef float f32x4 __attribute__((ext_vector_type(4)));
typedef __bf16 bf16x8 __attribute__((ext_vector_type(8)));

// fp32 -> bf16 RNE
__device__ __forceinline__ unsigned short f2bf(float f){
  unsigned int u = __builtin_bit_cast(unsigned int, f);
  u += 0x7fffu + ((u >> 16) & 1u);
  return (unsigned short)(u >> 16);
}
__device__ __forceinline__ float bf2f(unsigned short h){
  return __builtin_bit_cast(float, (unsigned int)h << 16);
}

__device__ __forceinline__ void glds16(const void* g, void* l){
  __builtin_amdgcn_global_load_lds((const __attribute__((address_space(1))) void*)g,
                                   (__attribute__((address_space(3))) void*)l, 16, 0, 0);
}

__device__ __forceinline__ f32x4 mfma16(bf16x8 a, bf16x8 b, f32x4 c){
  return __builtin_amdgcn_mfma_f32_16x16x32_bf16(a, b, c, 0, 0, 0);
}

#if __has_builtin(__builtin_amdgcn_exp2f)
__device__ __forceinline__ float exp2v(float x){ return __builtin_amdgcn_exp2f(x); }
#else
__device__ __forceinline__ float exp2v(float x){ return exp2f(x); }
#endif

// packed f32x2 -> bf16x2 (gfx950)
__device__ __forceinline__ unsigned int cvtpk(float a, float b){
  unsigned int r;
  asm("v_cvt_pk_bf16_f32 %0, %1, %2" : "=v"(r) : "v"(a), "v"(b));
  return r;
}

// ---------- kernel: detect mask dtype (bool-bytes vs int32) ----------
__global__ void detect_kernel(const unsigned int* __restrict__ m, int* __restrict__ flag){
  int t = threadIdx.x;
  int bad = 0;
  for(int i = t; i < 4096; i += 256) bad |= (m[i] > 1u);
  unsigned long long b = __ballot(bad != 0);
  __shared__ int sbuf[4];
  if((t & 63) == 0) sbuf[t >> 6] = (b != 0ull);
  __syncthreads();
  if(t == 0) flag[0] = (sbuf[0] | sbuf[1] | sbuf[2] | sbuf[3]) ? 0 : 1; // 1 => int32
}

// ---------- kernel: pack mask into bits (mp[row][64 words]) ----------
__global__ void pack_mask_kernel(const unsigned char* __restrict__ m8,
                                 unsigned int* __restrict__ mp,
                                 const int* __restrict__ flag){
  const int wid = threadIdx.x >> 6, lane = threadIdx.x & 63;
  const int row = blockIdx.x * 4 + wid;            // 0..4095 (b*2048+q)
  const int is32 = flag[0];
  const int* m32 = (const int*)m8;
  for(int c0 = 0; c0 < 2048; c0 += 64){
    int mv = is32 ? m32[(size_t)row*2048 + c0 + lane]
                  : (int)m8[(size_t)row*2048 + c0 + lane];
    unsigned long long b = __ballot(mv != 0);
    if(lane == 0){
      mp[(size_t)row*64 + (c0 >> 5)]     = (unsigned int)b;
      mp[(size_t)row*64 + (c0 >> 5) + 1] = (unsigned int)(b >> 32);
    }
  }
}

// ---------- kernel: fp32 -> bf16 convert, all three of q/k/v ----------
__global__ void cvt3_kernel(const float* __restrict__ qs, const float* __restrict__ ks,
                            const float* __restrict__ vs, unsigned short* __restrict__ dst){
  const float* src = (blockIdx.y==0)?qs:(blockIdx.y==1)?ks:vs;
  unsigned short* d = dst + (size_t)blockIdx.y * 4194304;
  int i = blockIdx.x * 256 + threadIdx.x;
  const float4* s = (const float4*)src;
  float4 a = s[2*i], b = s[2*i+1];
  union { unsigned short h[8]; uint4 v; } o;
  o.h[0]=f2bf(a.x); o.h[1]=f2bf(a.y); o.h[2]=f2bf(a.z); o.h[3]=f2bf(a.w);
  o.h[4]=f2bf(b.x); o.h[5]=f2bf(b.y); o.h[6]=f2bf(b.z); o.h[7]=f2bf(b.w);
  ((uint4*)d)[i] = o.v;
}

// ---------- kernel: W[1024][1024] f32 -> W^T bf16 ----------
__global__ void transW_kernel(const float* __restrict__ Wq, const float* __restrict__ Wk,
                              const float* __restrict__ Wv, const float* __restrict__ Wo,
                              unsigned short* __restrict__ WT){
  const float* W = (blockIdx.y==0)?Wq:(blockIdx.y==1)?Wk:(blockIdx.y==2)?Wv:Wo;
  unsigned short* D = WT + (size_t)blockIdx.y * 1048576;
  int r0 = (blockIdx.x >> 4) * 64, c0 = (blockIdx.x & 15) * 64;
  __shared__ unsigned short T[64][65];
  int t = threadIdx.x;
  {
    int r = t >> 2, cb = (t & 3) * 16;
    const float4* src = (const float4*)(W + (size_t)(r0 + r) * 1024 + (c0 + cb));
    float4 v0 = src[0], v1 = src[1], v2 = src[2], v3 = src[3];
    float vals[16] = {v0.x,v0.y,v0.z,v0.w, v1.x,v1.y,v1.z,v1.w,
                      v2.x,v2.y,v2.z,v2.w, v3.x,v3.y,v3.z,v3.w};
    #pragma unroll
    for(int j=0;j<16;j++) T[cb + j][r] = f2bf(vals[j]);
  }
  __syncthreads();
  {
    int c = t >> 2, rb = (t & 3) * 16;
    union { unsigned short h[16]; uint4 v[2]; } o;
    #pragma unroll
    for(int j=0;j<16;j++) o.h[j] = T[c][rb + j];
    uint4* dp = (uint4*)(D + (size_t)(c0 + c) * 1024 + (r0 + rb));
    dp[0] = o.v[0]; dp[1] = o.v[1];
  }
}

// ---------- kernel: per-head transpose Vb[token][1024] -> Vt[bh*64+d][2048] ----------
__global__ void transV_kernel(const unsigned short* __restrict__ Vb,
                              unsigned short* __restrict__ Vt){
  const int bh = blockIdx.y, b = bh >> 4, h = bh & 15;
  const int s0 = blockIdx.x * 64;
  __shared__ unsigned short T[64][68];
  const int t = threadIdx.x;
  {
    int r = t >> 2, cb = (t & 3) * 16;
    const uint4* src = (const uint4*)(Vb + (size_t)(b*2048 + s0 + r)*1024 + h*64 + cb);
    union { unsigned short h[16]; uint4 v[2]; } o;
    o.v[0] = src[0]; o.v[1] = src[1];
    uint2* dst = (uint2*)&T[r][cb];
    const uint2* sv = (const uint2*)o.h;
    dst[0]=sv[0]; dst[1]=sv[1]; dst[2]=sv[2]; dst[3]=sv[3];
  }
  __syncthreads();
  {
    int c = t >> 2, sb = (t & 3) * 16;
    union { unsigned short h[16]; uint4 v[2]; } o;
    #pragma unroll
    for(int j=0;j<16;j++) o.h[j] = T[sb + j][c];
    uint4* dp = (uint4*)(Vt + (size_t)(bh*64 + c)*2048 + s0 + sb);
    dp[0] = o.v[0]; dp[1] = o.v[1];
  }
}

// ---------- kernel: C[M=4096][N=1024] = A @ BT^T, bf16, 128x128 tile, BK=64 ----------
template<int OUTF32>
__global__ __launch_bounds__(256,2) void gemm_bt(
    const unsigned short* __restrict__ A0, const unsigned short* __restrict__ A1, const unsigned short* __restrict__ A2,
    const unsigned short* __restrict__ B0, const unsigned short* __restrict__ B1, const unsigned short* __restrict__ B2,
    unsigned short* __restrict__ C0, unsigned short* __restrict__ C1, unsigned short* __restrict__ C2,
    float* __restrict__ Cf)
{
  const unsigned short* A  = (blockIdx.z==0)?A0:(blockIdx.z==1)?A1:A2;
  const unsigned short* BT = (blockIdx.z==0)?B0:(blockIdx.z==1)?B1:B2;
  unsigned short* C        = (blockIdx.z==0)?C0:(blockIdx.z==1)?C1:C2;
  __shared__ unsigned short Asm[128*64];
  __shared__ unsigned short Bsm[128*64];
  const int wid = threadIdx.x >> 6, lane = threadIdx.x & 63;
  const int m0 = blockIdx.x * 128, n0 = blockIdx.y * 128;
  const int wrow = wid >> 1, wcol = wid & 1;
  const int li = lane & 15, lg = lane >> 4, li7 = lane & 7;
  f32x4 acc[4][4] = {};
  const int sr = lane >> 3;       // 0..7 (row within 8-row chunk)
  const int sc = lane & 7;        // 0..7 (16B block within 128B row)

  for(int kt = 0; kt < 16; ++kt){
    const int kofs = kt * 64;
    #pragma unroll
    for(int i=0;i<4;i++){
      int r = wid*32 + i*8 + sr;             // tile-local row; r&7 == sr
      int blk = sc ^ sr;                     // source-side swizzle
      glds16(A  + (size_t)(m0 + r)*1024 + kofs + blk*8, &Asm[(wid*32 + i*8)*64]);
      glds16(BT + (size_t)(n0 + r)*1024 + kofs + blk*8, &Bsm[(wid*32 + i*8)*64]);
    }
    __syncthreads();
    #pragma unroll
    for(int kk=0; kk<2; kk++){
      bf16x8 af[4], bfv[4];
      #pragma unroll
      for(int fm=0; fm<4; fm++){
        int row = wrow*64 + fm*16 + li;      // row&7 == li7
        int blk = (kk*4 + lg) ^ li7;
        af[fm] = *(const bf16x8*)&Asm[row*64 + blk*8];
      }
      #pragma unroll
      for(int fn=0; fn<4; fn++){
        int row = wcol*64 + fn*16 + li;
        int blk = (kk*4 + lg) ^ li7;
        bfv[fn] = *(const bf16x8*)&Bsm[row*64 + blk*8];
      }
      __builtin_amdgcn_s_setprio(1);
      #pragma unroll
      for(int fm=0; fm<4; fm++)
        #pragma unroll
        for(int fn=0; fn<4; fn++)
          acc[fm][fn] = mfma16(af[fm], bfv[fn], acc[fm][fn]);
      __builtin_amdgcn_s_setprio(0);
    }
    __syncthreads();
  }
  #pragma unroll
  for(int fm=0; fm<4; fm++){
    #pragma unroll
    for(int fn=0; fn<4; fn++){
      int col  = n0 + wcol*64 + fn*16 + li;
      int rowb = m0 + wrow*64 + fm*16 + lg*4;
      #pragma unroll
      for(int r=0;r<4;r++){
        if(OUTF32) Cf[(size_t)(rowb + r)*1024 + col] = acc[fm][fn][r];
        else       C [(size_t)(rowb + r)*1024 + col] = f2bf(acc[fm][fn][r]);
      }
    }
  }
}

// ---------- kernel: flash attention v5 (16x16 swapped-QK, split Psm, 36.8KB LDS) ----------
// grid 1024 (swizzled -> 32 qtiles x 32 bh), 4 waves x 16 q-rows, KVB=64, DK=64.
__global__ __launch_bounds__(256,4) void attn_kernel(
    const unsigned short* __restrict__ Q, const unsigned short* __restrict__ K,
    const unsigned short* __restrict__ Vt, unsigned short* __restrict__ O,
    const unsigned int* __restrict__ mp)
{
  __shared__ unsigned short Ksm[2][64*64];
  __shared__ unsigned short Vsm[2][64*64];
  __shared__ unsigned short Psm[4][16][32];   // per-wave half-P (one ks at a time)
  const int wid = threadIdx.x >> 6, lane = threadIdx.x & 63;
  const int orig = blockIdx.x;
  const int wg = (orig & 7) * 128 + (orig >> 3);   // XCD swizzle (1024 % 8 == 0)
  const int qt = wg & 31, bh = wg >> 5;
  const int b = bh >> 4, h = bh & 15;
  const int q0 = qt * 64;
  const int li = lane & 15, lg = lane >> 4;
  const int li7 = li & 7, li3 = li & 3;

  // Q fragment pre-scaled by 0.125*log2(e) -> scores in log2 domain
  bf16x8 qf[2];
  {
    const unsigned short* qp = Q + (size_t)(b*2048 + q0 + wid*16 + li)*1024 + h*64 + lg*8;
    union { unsigned short s[8]; bf16x8 v; } u0, u1;
    u0.v = *(const bf16x8*)qp; u1.v = *(const bf16x8*)(qp + 32);
    #pragma unroll
    for(int j=0;j<8;j++){
      u0.s[j] = f2bf(bf2f(u0.s[j]) * 0.1803368801111601f);
      u1.s[j] = f2bf(bf2f(u1.s[j]) * 0.1803368801111601f);
    }
    qf[0] = u0.v; qf[1] = u1.v;
  }

  f32x4 oacc[4] = {};
  float mrow = -__builtin_inff();
  float lrow = 0.f;                      // lane-partial row sum (quad-reduced at end)

  const int srow = lane >> 3;
  const int sblk = (lane & 7) ^ srow;    // source-side swizzle for K/V staging
  const int mrowg = b*2048 + q0 + wid*16 + li;   // this lane's q-row (mask row)

  // stage tile 0
  #pragma unroll
  for(int i=0;i<2;i++){
    int r = wid*16 + i*8 + srow;
    glds16(K  + (size_t)(b*2048 + r)*1024 + h*64 + sblk*8, &Ksm[0][(wid*16 + i*8)*64]);
    glds16(Vt + (size_t)(bh*64 + r)*2048 + sblk*8,         &Vsm[0][(wid*16 + i*8)*64]);
  }
  uint2 mw = *(const uint2*)&mp[(size_t)mrowg*64];
  uint2 mwn;
  __syncthreads();

  int buf = 0;
  for(int t = 0; t < 32; ++t){
    const int kv0 = t * 64;
    if(t < 31){
      #pragma unroll
      for(int i=0;i<2;i++){
        int r = wid*16 + i*8 + srow;
        glds16(K  + (size_t)(b*2048 + kv0 + 64 + r)*1024 + h*64 + sblk*8, &Ksm[buf^1][(wid*16 + i*8)*64]);
        glds16(Vt + (size_t)(bh*64 + r)*2048 + kv0 + 64 + sblk*8,         &Vsm[buf^1][(wid*16 + i*8)*64]);
      }
      mwn = *(const uint2*)&mp[(size_t)mrowg*64 + (size_t)((kv0 + 64) >> 5)];
    }
    // S^T tiles: p[f][j] = S[q=li][k=f*16+lg*4+j] (log2 domain)
    float p[4][4];
    __builtin_amdgcn_s_setprio(1);
    #pragma unroll
    for(int f=0; f<4; f++){
      f32x4 s = {0.f,0.f,0.f,0.f};
      #pragma unroll
      for(int kf=0; kf<2; kf++){
        int blk = (kf*4 + lg) ^ li7;
        bf16x8 kfr = *(const bf16x8*)&Ksm[buf][(f*16 + li)*64 + blk*8];
        s = mfma16(kfr, qf[kf], s);     // swapped operands
      }
      #pragma unroll
      for(int j=0;j<4;j++) p[f][j] = s[j];
    }
    __builtin_amdgcn_s_setprio(0);
    // mask (packed bits; lane owns one q-row)
    #pragma unroll
    for(int f=0; f<4; f++){
      unsigned int w = (f < 2) ? mw.x : mw.y;
      #pragma unroll
      for(int j=0;j<4;j++){
        unsigned int bit = (w >> ((f & 1)*16 + lg*4 + j)) & 1u;
        p[f][j] = bit ? -1.0e9f : p[f][j];
      }
    }
    // tile max (per-thread tree + 2 shfl across the quad)
    float tmax;
    {
      float m0 = fmaxf(fmaxf(p[0][0],p[0][1]), fmaxf(p[0][2],p[0][3]));
      float m1 = fmaxf(fmaxf(p[1][0],p[1][1]), fmaxf(p[1][2],p[1][3]));
      float m2 = fmaxf(fmaxf(p[2][0],p[2][1]), fmaxf(p[2][2],p[2][3]));
      float m3 = fmaxf(fmaxf(p[3][0],p[3][1]), fmaxf(p[3][2],p[3][3]));
      tmax = fmaxf(fmaxf(m0,m1), fmaxf(m2,m3));
      tmax = fmaxf(tmax, __shfl_xor(tmax, 16));
      tmax = fmaxf(tmax, __shfl_xor(tmax, 32));
    }
    // defer-rescale (T13): only rescale when max grows by > 8 (log2 units)
    if(__any(tmax > mrow + 8.f)){
      float mn = fmaxf(mrow, tmax);
      float scal = exp2v(mrow - mn);
      mrow = mn;
      lrow *= scal;
      float so0 = __shfl(scal, lg*4 + 0);
      float so1 = __shfl(scal, lg*4 + 1);
      float so2 = __shfl(scal, lg*4 + 2);
      float so3 = __shfl(scal, lg*4 + 3);
      #pragma unroll
      for(int d=0; d<4; d++){
        oacc[d][0] *= so0; oacc[d][1] *= so1; oacc[d][2] *= so2; oacc[d][3] *= so3;
      }
    }
    // per-ks-half: exp2 + pack -> Psm(4KB) -> pa read -> PV mfma
    float rs = 0.f;
    #pragma unroll
    for(int ks=0; ks<2; ks++){
      #pragma unroll
      for(int fl=0; fl<2; fl++){
        const int f = ks*2 + fl;
        float e0 = exp2v(p[f][0] - mrow);
        float e1 = exp2v(p[f][1] - mrow);
        float e2 = exp2v(p[f][2] - mrow);
        float e3 = exp2v(p[f][3] - mrow);
        rs += (e0 + e1) + (e2 + e3);
        unsigned int a0 = cvtpk(e0, e1);
        unsigned int a1 = cvtpk(e2, e3);
        int blk = (fl*2 + (lg >> 1)) ^ li3;
        uint2 w2; w2.x = a0; w2.y = a1;
        *(uint2*)&Psm[wid][li][blk*8 + (lg & 1)*4] = w2;
      }
      bf16x8 pa = *(const bf16x8*)&Psm[wid][li][(lg ^ li3)*8];
      __builtin_amdgcn_s_setprio(1);
      #pragma unroll
      for(int d=0; d<4; d++){
        int blk = (ks*4 + lg) ^ li7;
        bf16x8 vf = *(const bf16x8*)&Vsm[buf][(d*16 + li)*64 + blk*8];
        oacc[d] = mfma16(pa, vf, oacc[d]);
      }
      __builtin_amdgcn_s_setprio(0);
    }
    lrow += rs;
    __syncthreads();
    mw = mwn;
    buf ^= 1;
  }
  // reduce lane-partial sums across the quad, normalize, store
  float rs = lrow;
  rs += __shfl_xor(rs, 16);
  rs += __shfl_xor(rs, 32);
  float inv = 1.0f / rs;                 // valid for q-row li
  float io0 = __shfl(inv, lg*4 + 0);
  float io1 = __shfl(inv, lg*4 + 1);
  float io2 = __shfl(inv, lg*4 + 2);
  float io3 = __shfl(inv, lg*4 + 3);
  #pragma unroll
  for(int d=0; d<4; d++){
    size_t rb = (size_t)(b*2048 + q0 + wid*16 + lg*4);
    O[(rb+0)*1024 + h*64 + 16*d + li] = f2bf(oacc[d][0] * io0);
    O[(rb+1)*1024 + h*64 + 16*d + li] = f2bf(oacc[d][1] * io1);
    O[(rb+2)*1024 + h*64 + 16*d + li] = f2bf(oacc[d][2] * io2);
    O[(rb+3)*1024 + h*64 + 16*d + li] = f2bf(oacc[d][3] * io3);
  }
}

// ---------- launch ----------
extern "C" void kernel_launch(void* const* d_in, const int* in_sizes, int n_in,
                              void* d_out, int out_size, void* d_ws, size_t ws_size,
                              hipStream_t stream)
{
  const float* q_in = (const float*)d_in[0];
  const float* k_in = (const float*)d_in[1];
  const float* v_in = (const float*)d_in[2];
  const unsigned char* mask = (const unsigned char*)d_in[3];
  const float* Wq = (const float*)d_in[4];
  const float* Wk = (const float*)d_in[5];
  const float* Wv = (const float*)d_in[6];
  const float* Wo = (const float*)d_in[7];

  char* ws = (char*)d_ws;
  const size_t MB = 1024*1024;
  int* flag          = (int*)ws;                              // 256 B
  unsigned short* XQ = (unsigned short*)(ws + 256);           // 8 MB
  unsigned short* XK = (unsigned short*)(ws + 256 + 8*MB);    // 8 MB
  unsigned short* XV = (unsigned short*)(ws + 256 + 16*MB);   // 8 MB
  unsigned short* WT = (unsigned short*)(ws + 256 + 24*MB);   // 8 MB (4 matrices)
  unsigned short* Qb = (unsigned short*)(ws + 256 + 32*MB);   // 8 MB
  unsigned short* Kb = (unsigned short*)(ws + 256 + 40*MB);   // 8 MB
  unsigned short* Vb = (unsigned short*)(ws + 256 + 48*MB);   // 8 MB
  unsigned short* Ob = XQ;                                    // attention output
  unsigned short* Vt = XK;                                    // transposed V (8 MB)
  unsigned int*   mpk= (unsigned int*)XV;                     // packed mask (2 MB)

  detect_kernel<<<1, 256, 0, stream>>>((const unsigned int*)mask, flag);
  cvt3_kernel<<<dim3(2048,3), 256, 0, stream>>>(q_in, k_in, v_in, XQ);
  transW_kernel<<<dim3(256,4), 256, 0, stream>>>(Wq, Wk, Wv, Wo, WT);
  gemm_bt<0><<<dim3(32,8,3), 256, 0, stream>>>(XQ, XK, XV,
                                               WT, WT + 1048576, WT + 2097152,
                                               Qb, Kb, Vb, nullptr);
  transV_kernel<<<dim3(32,32), 256, 0, stream>>>(Vb, Vt);
  pack_mask_kernel<<<1024, 256, 0, stream>>>(mask, mpk, flag);
  attn_kernel<<<1024, 256, 0, stream>>>(Qb, Kb, Vt, Ob, mpk);
  gemm_bt<1><<<dim3(32,8,1), 256, 0, stream>>>(Ob, Ob, Ob,
                                               WT + 3*1048576, WT + 3*1048576, WT + 3*1048576,
                                               nullptr, nullptr, nullptr, (float*)d_out);
}

// Round 6
// 152.964 us; speedup vs baseline: 1.1518x; 1.0569x over previous
//
#include <hip/hip_runtime.h>
#include <hip/hip_bf16.h>

// ---------- types ----------
typedef float f32x4 __attribute__((ext_vector_type(4)));
typedef __bf16 bf16x8 __attribute__((ext_vector_type(8)));

// fp32 -> bf16 RNE
__device__ __forceinline__ unsigned short f2bf(float f){
  unsigned int u = __builtin_bit_cast(unsigned int, f);
  u += 0x7fffu + ((u >> 16) & 1u);
  return (unsigned short)(u >> 16);
}
__device__ __forceinline__ float bf2f(unsigned short h){
  return __builtin_bit_cast(float, (unsigned int)h << 16);
}

__device__ __forceinline__ void glds16(const void* g, void* l){
  __builtin_amdgcn_global_load_lds((const __attribute__((address_space(1))) void*)g,
                                   (__attribute__((address_space(3))) void*)l, 16, 0, 0);
}

__device__ __forceinline__ f32x4 mfma16(bf16x8 a, bf16x8 b, f32x4 c){
  return __builtin_amdgcn_mfma_f32_16x16x32_bf16(a, b, c, 0, 0, 0);
}

#if __has_builtin(__builtin_amdgcn_exp2f)
__device__ __forceinline__ float exp2v(float x){ return __builtin_amdgcn_exp2f(x); }
#else
__device__ __forceinline__ float exp2v(float x){ return exp2f(x); }
#endif

// packed f32x2 -> bf16x2 (gfx950)
__device__ __forceinline__ unsigned int cvtpk(float a, float b){
  unsigned int r;
  asm("v_cvt_pk_bf16_f32 %0, %1, %2" : "=v"(r) : "v"(a), "v"(b));
  return r;
}

// ---------- kernel: detect mask dtype (bool-bytes vs int32) ----------
__global__ void detect_kernel(const unsigned int* __restrict__ m, int* __restrict__ flag){
  int t = threadIdx.x;
  int bad = 0;
  for(int i = t; i < 4096; i += 256) bad |= (m[i] > 1u);
  unsigned long long b = __ballot(bad != 0);
  __shared__ int sbuf[4];
  if((t & 63) == 0) sbuf[t >> 6] = (b != 0ull);
  __syncthreads();
  if(t == 0) flag[0] = (sbuf[0] | sbuf[1] | sbuf[2] | sbuf[3]) ? 0 : 1; // 1 => int32
}

// ---------- kernel: pack mask into bits (mp[row][64 words]) ----------
__global__ void pack_mask_kernel(const unsigned char* __restrict__ m8,
                                 unsigned int* __restrict__ mp,
                                 const int* __restrict__ flag){
  const int wid = threadIdx.x >> 6, lane = threadIdx.x & 63;
  const int row = blockIdx.x * 4 + wid;            // 0..4095 (b*2048+q)
  const int is32 = flag[0];
  const int* m32 = (const int*)m8;
  for(int c0 = 0; c0 < 2048; c0 += 64){
    int mv = is32 ? m32[(size_t)row*2048 + c0 + lane]
                  : (int)m8[(size_t)row*2048 + c0 + lane];
    unsigned long long b = __ballot(mv != 0);
    if(lane == 0){
      mp[(size_t)row*64 + (c0 >> 5)]     = (unsigned int)b;
      mp[(size_t)row*64 + (c0 >> 5) + 1] = (unsigned int)(b >> 32);
    }
  }
}

// ---------- kernel: fp32 -> bf16 convert, all three of q/k/v ----------
__global__ void cvt3_kernel(const float* __restrict__ qs, const float* __restrict__ ks,
                            const float* __restrict__ vs, unsigned short* __restrict__ dst){
  const float* src = (blockIdx.y==0)?qs:(blockIdx.y==1)?ks:vs;
  unsigned short* d = dst + (size_t)blockIdx.y * 4194304;
  int i = blockIdx.x * 256 + threadIdx.x;
  const float4* s = (const float4*)src;
  float4 a = s[2*i], b = s[2*i+1];
  union { unsigned short h[8]; uint4 v; } o;
  o.h[0]=f2bf(a.x); o.h[1]=f2bf(a.y); o.h[2]=f2bf(a.z); o.h[3]=f2bf(a.w);
  o.h[4]=f2bf(b.x); o.h[5]=f2bf(b.y); o.h[6]=f2bf(b.z); o.h[7]=f2bf(b.w);
  ((uint4*)d)[i] = o.v;
}

// ---------- kernel: W[1024][1024] f32 -> W^T bf16 (Wq scaled by 0.125*log2e) ----------
__global__ void transW_kernel(const float* __restrict__ Wq, const float* __restrict__ Wk,
                              const float* __restrict__ Wv, const float* __restrict__ Wo,
                              unsigned short* __restrict__ WT){
  const float* W = (blockIdx.y==0)?Wq:(blockIdx.y==1)?Wk:(blockIdx.y==2)?Wv:Wo;
  const float scale = (blockIdx.y==0) ? 0.1803368801111601f : 1.0f;
  unsigned short* D = WT + (size_t)blockIdx.y * 1048576;
  int r0 = (blockIdx.x >> 4) * 64, c0 = (blockIdx.x & 15) * 64;
  __shared__ unsigned short T[64][65];
  int t = threadIdx.x;
  {
    int r = t >> 2, cb = (t & 3) * 16;
    const float4* src = (const float4*)(W + (size_t)(r0 + r) * 1024 + (c0 + cb));
    float4 v0 = src[0], v1 = src[1], v2 = src[2], v3 = src[3];
    float vals[16] = {v0.x,v0.y,v0.z,v0.w, v1.x,v1.y,v1.z,v1.w,
                      v2.x,v2.y,v2.z,v2.w, v3.x,v3.y,v3.z,v3.w};
    #pragma unroll
    for(int j=0;j<16;j++) T[cb + j][r] = f2bf(vals[j] * scale);
  }
  __syncthreads();
  {
    int c = t >> 2, rb = (t & 3) * 16;
    union { unsigned short h[16]; uint4 v[2]; } o;
    #pragma unroll
    for(int j=0;j<16;j++) o.h[j] = T[c][rb + j];
    uint4* dp = (uint4*)(D + (size_t)(c0 + c) * 1024 + (r0 + rb));
    dp[0] = o.v[0]; dp[1] = o.v[1];
  }
}

// ---------- kernel: C[M=4096][N=1024] = A @ BT^T, bf16, 128x128 tile, BK=64 ----------
// OUTF32=1: f32 store to Cf.  OUTF32=0: bf16 store; blockIdx.z==2 writes per-head
// transposed V directly: Vt[(b*16+h)*64+d][s].
template<int OUTF32>
__global__ __launch_bounds__(256,2) void gemm_bt(
    const unsigned short* __restrict__ A0, const unsigned short* __restrict__ A1, const unsigned short* __restrict__ A2,
    const unsigned short* __restrict__ B0, const unsigned short* __restrict__ B1, const unsigned short* __restrict__ B2,
    unsigned short* __restrict__ C0, unsigned short* __restrict__ C1, unsigned short* __restrict__ C2,
    float* __restrict__ Cf)
{
  const unsigned short* A  = (blockIdx.z==0)?A0:(blockIdx.z==1)?A1:A2;
  const unsigned short* BT = (blockIdx.z==0)?B0:(blockIdx.z==1)?B1:B2;
  unsigned short* C        = (blockIdx.z==0)?C0:(blockIdx.z==1)?C1:C2;
  __shared__ unsigned short Asm[128*64];
  __shared__ unsigned short Bsm[128*64];
  const int wid = threadIdx.x >> 6, lane = threadIdx.x & 63;
  const int m0 = blockIdx.x * 128, n0 = blockIdx.y * 128;
  const int wrow = wid >> 1, wcol = wid & 1;
  const int li = lane & 15, lg = lane >> 4, li7 = lane & 7;
  f32x4 acc[4][4] = {};
  const int sr = lane >> 3;       // 0..7 (row within 8-row chunk)
  const int sc = lane & 7;        // 0..7 (16B block within 128B row)

  for(int kt = 0; kt < 16; ++kt){
    const int kofs = kt * 64;
    #pragma unroll
    for(int i=0;i<4;i++){
      int r = wid*32 + i*8 + sr;             // tile-local row; r&7 == sr
      int blk = sc ^ sr;                     // source-side swizzle
      glds16(A  + (size_t)(m0 + r)*1024 + kofs + blk*8, &Asm[(wid*32 + i*8)*64]);
      glds16(BT + (size_t)(n0 + r)*1024 + kofs + blk*8, &Bsm[(wid*32 + i*8)*64]);
    }
    __syncthreads();
    #pragma unroll
    for(int kk=0; kk<2; kk++){
      bf16x8 af[4], bfv[4];
      #pragma unroll
      for(int fm=0; fm<4; fm++){
        int row = wrow*64 + fm*16 + li;      // row&7 == li7
        int blk = (kk*4 + lg) ^ li7;
        af[fm] = *(const bf16x8*)&Asm[row*64 + blk*8];
      }
      #pragma unroll
      for(int fn=0; fn<4; fn++){
        int row = wcol*64 + fn*16 + li;
        int blk = (kk*4 + lg) ^ li7;
        bfv[fn] = *(const bf16x8*)&Bsm[row*64 + blk*8];
      }
      __builtin_amdgcn_s_setprio(1);
      #pragma unroll
      for(int fm=0; fm<4; fm++)
        #pragma unroll
        for(int fn=0; fn<4; fn++)
          acc[fm][fn] = mfma16(af[fm], bfv[fn], acc[fm][fn]);
      __builtin_amdgcn_s_setprio(0);
    }
    __syncthreads();
  }
  if(OUTF32 == 0 && blockIdx.z == 2){
    // V: write transposed per head.  4 consecutive s-rows pack to one 8B store.
    #pragma unroll
    for(int fm=0; fm<4; fm++){
      #pragma unroll
      for(int fn=0; fn<4; fn++){
        int col  = n0 + wcol*64 + fn*16 + li;        // h*64 + d
        int rowb = m0 + wrow*64 + fm*16 + lg*4;      // b*2048 + s
        int bq = rowb >> 11, s = rowb & 2047;
        union { unsigned short h[4]; unsigned long long u; } o;
        #pragma unroll
        for(int r=0;r<4;r++) o.h[r] = f2bf(acc[fm][fn][r]);
        *(unsigned long long*)&C[((size_t)(bq*16 + (col>>6))*64 + (col&63))*2048 + s] = o.u;
      }
    }
  } else {
    #pragma unroll
    for(int fm=0; fm<4; fm++){
      #pragma unroll
      for(int fn=0; fn<4; fn++){
        int col  = n0 + wcol*64 + fn*16 + li;
        int rowb = m0 + wrow*64 + fm*16 + lg*4;
        #pragma unroll
        for(int r=0;r<4;r++){
          if(OUTF32) Cf[(size_t)(rowb + r)*1024 + col] = acc[fm][fn][r];
          else       C [(size_t)(rowb + r)*1024 + col] = f2bf(acc[fm][fn][r]);
        }
      }
    }
  }
}

// ---------- kernel: flash attention v6 ----------
// 16x16 swapped-QK, fixed-exponent softmax (no online max), P exchanged fully
// in-register (no Psm). LDS = 32768 B exactly -> 4 blocks/CU at grid 1024.
// grid 1024 (swizzled -> 32 qtiles x 32 bh), 4 waves x 16 q-rows, KVB=64, DK=64.
__global__ __launch_bounds__(256,4) void attn_kernel(
    const unsigned short* __restrict__ Q, const unsigned short* __restrict__ K,
    const unsigned short* __restrict__ Vt, unsigned short* __restrict__ O,
    const unsigned int* __restrict__ mp)
{
  __shared__ unsigned short Ksm[2][64*64];
  __shared__ unsigned short Vsm[2][64*64];
  const int wid = threadIdx.x >> 6, lane = threadIdx.x & 63;
  const int orig = blockIdx.x;
  const int wg = (orig & 7) * 128 + (orig >> 3);   // XCD swizzle (1024 % 8 == 0)
  const int qt = wg & 31, bh = wg >> 5;
  const int b = bh >> 4, h = bh & 15;
  const int q0 = qt * 64;
  const int li = lane & 15, lg = lane >> 4;
  const int li7 = li & 7;
  const int src0 = li + 32*(lg & 1);     // P-exchange partner lanes
  const int src1 = src0 + 16;
  const int hiSel = lg >> 1;

  // Q fragment (Wq already carries 0.125*log2e -> scores in log2 domain)
  bf16x8 qf[2];
  {
    const unsigned short* qp = Q + (size_t)(b*2048 + q0 + wid*16 + li)*1024 + h*64 + lg*8;
    qf[0] = *(const bf16x8*)qp;
    qf[1] = *(const bf16x8*)(qp + 32);
  }

  f32x4 oacc[4] = {};
  float lrow = 0.f;                      // lane-partial row sum (quad-reduced at end)

  const int srow = lane >> 3;
  const int sblk = (lane & 7) ^ srow;    // source-side swizzle for K/V staging
  const int mrowg = b*2048 + q0 + wid*16 + li;   // this lane's q-row (mask row)

  // stage tile 0
  #pragma unroll
  for(int i=0;i<2;i++){
    int r = wid*16 + i*8 + srow;
    glds16(K  + (size_t)(b*2048 + r)*1024 + h*64 + sblk*8, &Ksm[0][(wid*16 + i*8)*64]);
    glds16(Vt + (size_t)(bh*64 + r)*2048 + sblk*8,         &Vsm[0][(wid*16 + i*8)*64]);
  }
  uint2 mw = *(const uint2*)&mp[(size_t)mrowg*64];
  uint2 mwn;
  __syncthreads();

  int buf = 0;
  for(int t = 0; t < 32; ++t){
    const int kv0 = t * 64;
    if(t < 31){
      #pragma unroll
      for(int i=0;i<2;i++){
        int r = wid*16 + i*8 + srow;
        glds16(K  + (size_t)(b*2048 + kv0 + 64 + r)*1024 + h*64 + sblk*8, &Ksm[buf^1][(wid*16 + i*8)*64]);
        glds16(Vt + (size_t)(bh*64 + r)*2048 + kv0 + 64 + sblk*8,         &Vsm[buf^1][(wid*16 + i*8)*64]);
      }
      mwn = *(const uint2*)&mp[(size_t)mrowg*64 + (size_t)((kv0 + 64) >> 5)];
    }
    // S^T tiles: p[f][j] = S[q=li][k=f*16+lg*4+j] (log2 domain)
    float p[4][4];
    __builtin_amdgcn_s_setprio(1);
    #pragma unroll
    for(int f=0; f<4; f++){
      f32x4 s = {0.f,0.f,0.f,0.f};
      #pragma unroll
      for(int kf=0; kf<2; kf++){
        int blk = (kf*4 + lg) ^ li7;
        bf16x8 kfr = *(const bf16x8*)&Ksm[buf][(f*16 + li)*64 + blk*8];
        s = mfma16(kfr, qf[kf], s);     // swapped operands
      }
      #pragma unroll
      for(int j=0;j<4;j++) p[f][j] = s[j];
    }
    __builtin_amdgcn_s_setprio(0);
    // fixed-exponent softmax: e = masked ? 0 : exp2(s); lane-partial sum
    unsigned int Af[4], Bf[4];
    {
      float rs = 0.f;
      #pragma unroll
      for(int f=0; f<4; f++){
        unsigned int w = (f < 2) ? mw.x : mw.y;
        float e[4];
        #pragma unroll
        for(int j=0;j<4;j++){
          unsigned int bit = (w >> ((f & 1)*16 + lg*4 + j)) & 1u;
          float v = exp2v(p[f][j]);
          e[j] = bit ? 0.f : v;
          rs += e[j];
        }
        Af[f] = cvtpk(e[0], e[1]);
        Bf[f] = cvtpk(e[2], e[3]);
      }
      lrow += rs;
    }
    // O += P V ; P A-fragments gathered in-register from partner lanes
    #pragma unroll
    for(int ks=0; ks<2; ks++){
      unsigned int a0 = __shfl(Af[ks*2],   src0);
      unsigned int a1 = __shfl(Af[ks*2+1], src0);
      unsigned int b0 = __shfl(Bf[ks*2],   src0);
      unsigned int b1 = __shfl(Bf[ks*2+1], src0);
      unsigned int c0 = __shfl(Af[ks*2],   src1);
      unsigned int c1 = __shfl(Af[ks*2+1], src1);
      unsigned int d0 = __shfl(Bf[ks*2],   src1);
      unsigned int d1 = __shfl(Bf[ks*2+1], src1);
      union { unsigned int w[4]; bf16x8 v; } pa;
      pa.w[0] = hiSel ? a1 : a0;
      pa.w[1] = hiSel ? b1 : b0;
      pa.w[2] = hiSel ? c1 : c0;
      pa.w[3] = hiSel ? d1 : d0;
      __builtin_amdgcn_s_setprio(1);
      #pragma unroll
      for(int d=0; d<4; d++){
        int blk = (ks*4 + lg) ^ li7;
        bf16x8 vf = *(const bf16x8*)&Vsm[buf][(d*16 + li)*64 + blk*8];
        oacc[d] = mfma16(pa.v, vf, oacc[d]);
      }
      __builtin_amdgcn_s_setprio(0);
    }
    __syncthreads();
    mw = mwn;
    buf ^= 1;
  }
  // reduce lane-partial sums across the quad, normalize, store
  float rs = lrow;
  rs += __shfl_xor(rs, 16);
  rs += __shfl_xor(rs, 32);
  float inv = 1.0f / rs;                 // valid for q-row li
  float io0 = __shfl(inv, lg*4 + 0);
  float io1 = __shfl(inv, lg*4 + 1);
  float io2 = __shfl(inv, lg*4 + 2);
  float io3 = __shfl(inv, lg*4 + 3);
  #pragma unroll
  for(int d=0; d<4; d++){
    size_t rb = (size_t)(b*2048 + q0 + wid*16 + lg*4);
    O[(rb+0)*1024 + h*64 + 16*d + li] = f2bf(oacc[d][0] * io0);
    O[(rb+1)*1024 + h*64 + 16*d + li] = f2bf(oacc[d][1] * io1);
    O[(rb+2)*1024 + h*64 + 16*d + li] = f2bf(oacc[d][2] * io2);
    O[(rb+3)*1024 + h*64 + 16*d + li] = f2bf(oacc[d][3] * io3);
  }
}

// ---------- launch ----------
extern "C" void kernel_launch(void* const* d_in, const int* in_sizes, int n_in,
                              void* d_out, int out_size, void* d_ws, size_t ws_size,
                              hipStream_t stream)
{
  const float* q_in = (const float*)d_in[0];
  const float* k_in = (const float*)d_in[1];
  const float* v_in = (const float*)d_in[2];
  const unsigned char* mask = (const unsigned char*)d_in[3];
  const float* Wq = (const float*)d_in[4];
  const float* Wk = (const float*)d_in[5];
  const float* Wv = (const float*)d_in[6];
  const float* Wo = (const float*)d_in[7];

  char* ws = (char*)d_ws;
  const size_t MB = 1024*1024;
  int* flag          = (int*)ws;                              // 256 B
  unsigned short* XQ = (unsigned short*)(ws + 256);           // 8 MB
  unsigned short* XK = (unsigned short*)(ws + 256 + 8*MB);    // 8 MB
  unsigned short* XV = (unsigned short*)(ws + 256 + 16*MB);   // 8 MB
  unsigned short* WT = (unsigned short*)(ws + 256 + 24*MB);   // 8 MB (4 matrices)
  unsigned short* Qb = (unsigned short*)(ws + 256 + 32*MB);   // 8 MB
  unsigned short* Kb = (unsigned short*)(ws + 256 + 40*MB);   // 8 MB
  unsigned short* Vt = (unsigned short*)(ws + 256 + 48*MB);   // 8 MB (transposed V, direct from GEMM)
  unsigned short* Ob = XQ;                                    // attention output
  unsigned int*   mpk= (unsigned int*)XV;                     // packed mask (2 MB, written after GEMM reads XV)

  detect_kernel<<<1, 256, 0, stream>>>((const unsigned int*)mask, flag);
  cvt3_kernel<<<dim3(2048,3), 256, 0, stream>>>(q_in, k_in, v_in, XQ);
  transW_kernel<<<dim3(256,4), 256, 0, stream>>>(Wq, Wk, Wv, Wo, WT);
  gemm_bt<0><<<dim3(32,8,3), 256, 0, stream>>>(XQ, XK, XV,
                                               WT, WT + 1048576, WT + 2097152,
                                               Qb, Kb, Vt, nullptr);
  pack_mask_kernel<<<1024, 256, 0, stream>>>(mask, mpk, flag);
  attn_kernel<<<1024, 256, 0, stream>>>(Qb, Kb, Vt, Ob, mpk);
  gemm_bt<1><<<dim3(32,8,1), 256, 0, stream>>>(Ob, Ob, Ob,
                                               WT + 3*1048576, WT + 3*1048576, WT + 3*1048576,
                                               nullptr, nullptr, nullptr, (float*)d_out);
}

// Round 8
// 142.289 us; speedup vs baseline: 1.2382x; 1.0750x over previous
//
#include <hip/hip_runtime.h>
#include <hip/hip_bf16.h>

// ---------- types ----------
typedef float f32x4 __attribute__((ext_vector_type(4)));
typedef __bf16 bf16x8 __attribute__((ext_vector_type(8)));
typedef _Float16 f16x2 __attribute__((ext_vector_type(2)));
typedef _Float16 f16x4 __attribute__((ext_vector_type(4)));

// fp32 -> bf16 RNE
__device__ __forceinline__ unsigned short f2bf(float f){
  unsigned int u = __builtin_bit_cast(unsigned int, f);
  u += 0x7fffu + ((u >> 16) & 1u);
  return (unsigned short)(u >> 16);
}
__device__ __forceinline__ float bf2f(unsigned short h){
  return __builtin_bit_cast(float, (unsigned int)h << 16);
}

// packed f32x2 -> f16x2 (v_cvt_pkrtz_f16_f32), with type-identity fix
__device__ __forceinline__ f16x2 pkrtz(float a, float b){
  return __builtin_bit_cast(f16x2, __builtin_amdgcn_cvt_pkrtz(a, b));
}

__device__ __forceinline__ void glds16(const void* g, void* l){
  __builtin_amdgcn_global_load_lds((const __attribute__((address_space(1))) void*)g,
                                   (__attribute__((address_space(3))) void*)l, 16, 0, 0);
}

__device__ __forceinline__ f32x4 mfma16(bf16x8 a, bf16x8 b, f32x4 c){
  return __builtin_amdgcn_mfma_f32_16x16x32_bf16(a, b, c, 0, 0, 0);
}
__device__ __forceinline__ f32x4 mfma16h(f16x4 a, f16x4 b, f32x4 c){
  return __builtin_amdgcn_mfma_f32_16x16x16f16(a, b, c, 0, 0, 0);
}

#if __has_builtin(__builtin_amdgcn_exp2f)
__device__ __forceinline__ float exp2v(float x){ return __builtin_amdgcn_exp2f(x); }
#else
__device__ __forceinline__ float exp2v(float x){ return exp2f(x); }
#endif

// ---------- kernel: detect mask dtype (bool-bytes vs int32) ----------
__global__ void detect_kernel(const unsigned int* __restrict__ m, int* __restrict__ flag){
  int t = threadIdx.x;
  int bad = 0;
  for(int i = t; i < 4096; i += 256) bad |= (m[i] > 1u);
  unsigned long long b = __ballot(bad != 0);
  __shared__ int sbuf[4];
  if((t & 63) == 0) sbuf[t >> 6] = (b != 0ull);
  __syncthreads();
  if(t == 0) flag[0] = (sbuf[0] | sbuf[1] | sbuf[2] | sbuf[3]) ? 0 : 1; // 1 => int32
}

// ---------- kernel: pack mask into bits (mp[row][64 words]) ----------
__global__ void pack_mask_kernel(const unsigned char* __restrict__ m8,
                                 unsigned int* __restrict__ mp,
                                 const int* __restrict__ flag){
  const int wid = threadIdx.x >> 6, lane = threadIdx.x & 63;
  const int row = blockIdx.x * 4 + wid;            // 0..4095 (b*2048+q)
  const int is32 = flag[0];
  const int* m32 = (const int*)m8;
  for(int c0 = 0; c0 < 2048; c0 += 64){
    int mv = is32 ? m32[(size_t)row*2048 + c0 + lane]
                  : (int)m8[(size_t)row*2048 + c0 + lane];
    unsigned long long b = __ballot(mv != 0);
    if(lane == 0){
      mp[(size_t)row*64 + (c0 >> 5)]     = (unsigned int)b;
      mp[(size_t)row*64 + (c0 >> 5) + 1] = (unsigned int)(b >> 32);
    }
  }
}

// ---------- kernel: fp32 -> bf16 convert, all three of q/k/v ----------
__global__ void cvt3_kernel(const float* __restrict__ qs, const float* __restrict__ ks,
                            const float* __restrict__ vs, unsigned short* __restrict__ dst){
  const float* src = (blockIdx.y==0)?qs:(blockIdx.y==1)?ks:vs;
  unsigned short* d = dst + (size_t)blockIdx.y * 4194304;
  int i = blockIdx.x * 256 + threadIdx.x;
  const float4* s = (const float4*)src;
  float4 a = s[2*i], b = s[2*i+1];
  union { unsigned short h[8]; uint4 v; } o;
  o.h[0]=f2bf(a.x); o.h[1]=f2bf(a.y); o.h[2]=f2bf(a.z); o.h[3]=f2bf(a.w);
  o.h[4]=f2bf(b.x); o.h[5]=f2bf(b.y); o.h[6]=f2bf(b.z); o.h[7]=f2bf(b.w);
  ((uint4*)d)[i] = o.v;
}

// ---------- kernel: W[1024][1024] f32 -> W^T bf16 (Wq scaled by 0.125*log2e) ----------
__global__ void transW_kernel(const float* __restrict__ Wq, const float* __restrict__ Wk,
                              const float* __restrict__ Wv, const float* __restrict__ Wo,
                              unsigned short* __restrict__ WT){
  const float* W = (blockIdx.y==0)?Wq:(blockIdx.y==1)?Wk:(blockIdx.y==2)?Wv:Wo;
  const float scale = (blockIdx.y==0) ? 0.1803368801111601f : 1.0f;
  unsigned short* D = WT + (size_t)blockIdx.y * 1048576;
  int r0 = (blockIdx.x >> 4) * 64, c0 = (blockIdx.x & 15) * 64;
  __shared__ unsigned short T[64][65];
  int t = threadIdx.x;
  {
    int r = t >> 2, cb = (t & 3) * 16;
    const float4* src = (const float4*)(W + (size_t)(r0 + r) * 1024 + (c0 + cb));
    float4 v0 = src[0], v1 = src[1], v2 = src[2], v3 = src[3];
    float vals[16] = {v0.x,v0.y,v0.z,v0.w, v1.x,v1.y,v1.z,v1.w,
                      v2.x,v2.y,v2.z,v2.w, v3.x,v3.y,v3.z,v3.w};
    #pragma unroll
    for(int j=0;j<16;j++) T[cb + j][r] = f2bf(vals[j] * scale);
  }
  __syncthreads();
  {
    int c = t >> 2, rb = (t & 3) * 16;
    union { unsigned short h[16]; uint4 v[2]; } o;
    #pragma unroll
    for(int j=0;j<16;j++) o.h[j] = T[c][rb + j];
    uint4* dp = (uint4*)(D + (size_t)(c0 + c) * 1024 + (r0 + rb));
    dp[0] = o.v[0]; dp[1] = o.v[1];
  }
}

// ---------- kernel: C[M=4096][N=1024] = A @ BT^T, bf16, 128x128 tile, BK=64 ----------
// OUTF32=1: f32 store to Cf.  OUTF32=0: bf16 store; blockIdx.z==2 writes per-head
// transposed V as F16 directly: Vt[(b*16+h)*64+d][s].
template<int OUTF32>
__global__ __launch_bounds__(256,2) void gemm_bt(
    const unsigned short* __restrict__ A0, const unsigned short* __restrict__ A1, const unsigned short* __restrict__ A2,
    const unsigned short* __restrict__ B0, const unsigned short* __restrict__ B1, const unsigned short* __restrict__ B2,
    unsigned short* __restrict__ C0, unsigned short* __restrict__ C1, unsigned short* __restrict__ C2,
    float* __restrict__ Cf)
{
  const unsigned short* A  = (blockIdx.z==0)?A0:(blockIdx.z==1)?A1:A2;
  const unsigned short* BT = (blockIdx.z==0)?B0:(blockIdx.z==1)?B1:B2;
  unsigned short* C        = (blockIdx.z==0)?C0:(blockIdx.z==1)?C1:C2;
  __shared__ unsigned short Asm[128*64];
  __shared__ unsigned short Bsm[128*64];
  const int wid = threadIdx.x >> 6, lane = threadIdx.x & 63;
  const int m0 = blockIdx.x * 128, n0 = blockIdx.y * 128;
  const int wrow = wid >> 1, wcol = wid & 1;
  const int li = lane & 15, lg = lane >> 4, li7 = lane & 7;
  f32x4 acc[4][4] = {};
  const int sr = lane >> 3;       // 0..7 (row within 8-row chunk)
  const int sc = lane & 7;        // 0..7 (16B block within 128B row)

  for(int kt = 0; kt < 16; ++kt){
    const int kofs = kt * 64;
    #pragma unroll
    for(int i=0;i<4;i++){
      int r = wid*32 + i*8 + sr;             // tile-local row; r&7 == sr
      int blk = sc ^ sr;                     // source-side swizzle
      glds16(A  + (size_t)(m0 + r)*1024 + kofs + blk*8, &Asm[(wid*32 + i*8)*64]);
      glds16(BT + (size_t)(n0 + r)*1024 + kofs + blk*8, &Bsm[(wid*32 + i*8)*64]);
    }
    __syncthreads();
    #pragma unroll
    for(int kk=0; kk<2; kk++){
      bf16x8 af[4], bfv[4];
      #pragma unroll
      for(int fm=0; fm<4; fm++){
        int row = wrow*64 + fm*16 + li;      // row&7 == li7
        int blk = (kk*4 + lg) ^ li7;
        af[fm] = *(const bf16x8*)&Asm[row*64 + blk*8];
      }
      #pragma unroll
      for(int fn=0; fn<4; fn++){
        int row = wcol*64 + fn*16 + li;
        int blk = (kk*4 + lg) ^ li7;
        bfv[fn] = *(const bf16x8*)&Bsm[row*64 + blk*8];
      }
      __builtin_amdgcn_s_setprio(1);
      #pragma unroll
      for(int fm=0; fm<4; fm++)
        #pragma unroll
        for(int fn=0; fn<4; fn++)
          acc[fm][fn] = mfma16(af[fm], bfv[fn], acc[fm][fn]);
      __builtin_amdgcn_s_setprio(0);
    }
    __syncthreads();
  }
  if(OUTF32 == 0 && blockIdx.z == 2){
    // V: write transposed per head in F16.  4 consecutive s-rows pack to one 8B store.
    #pragma unroll
    for(int fm=0; fm<4; fm++){
      #pragma unroll
      for(int fn=0; fn<4; fn++){
        int col  = n0 + wcol*64 + fn*16 + li;        // h*64 + d
        int rowb = m0 + wrow*64 + fm*16 + lg*4;      // b*2048 + s
        int bq = rowb >> 11, s = rowb & 2047;
        union { f16x2 h2[2]; unsigned long long u; } o;
        o.h2[0] = pkrtz(acc[fm][fn][0], acc[fm][fn][1]);
        o.h2[1] = pkrtz(acc[fm][fn][2], acc[fm][fn][3]);
        *(unsigned long long*)&C[((size_t)(bq*16 + (col>>6))*64 + (col&63))*2048 + s] = o.u;
      }
    }
  } else {
    #pragma unroll
    for(int fm=0; fm<4; fm++){
      #pragma unroll
      for(int fn=0; fn<4; fn++){
        int col  = n0 + wcol*64 + fn*16 + li;
        int rowb = m0 + wrow*64 + fm*16 + lg*4;
        #pragma unroll
        for(int r=0;r<4;r++){
          if(OUTF32) Cf[(size_t)(rowb + r)*1024 + col] = acc[fm][fn][r];
          else       C [(size_t)(rowb + r)*1024 + col] = f2bf(acc[fm][fn][r]);
        }
      }
    }
  }
}

// ---------- kernel: flash attention v7 ----------
// 16x16 swapped-QK, fixed-exponent softmax, 2 q-tiles per wave (32 q-rows),
// PV via mfma_f32_16x16x16_f16 with P fully lane-local (zero exchange).
// grid 512 (swizzled -> 16 qtiles x 32 bh), 4 waves, QBLK=128, KVB=64, DK=64.
__global__ __launch_bounds__(256,2) void attn_kernel(
    const unsigned short* __restrict__ Q, const unsigned short* __restrict__ K,
    const unsigned short* __restrict__ Vt, unsigned short* __restrict__ O,
    const unsigned int* __restrict__ mp)
{
  __shared__ unsigned short Ksm[2][64*64];
  __shared__ unsigned short Vsm[2][64*64];     // f16 contents
  const int wid = threadIdx.x >> 6, lane = threadIdx.x & 63;
  const int orig = blockIdx.x;
  const int wg = (orig & 7) * 64 + (orig >> 3);    // XCD swizzle (512 % 8 == 0)
  const int qt = wg & 15, bh = wg >> 4;
  const int b = bh >> 4, h = bh & 15;
  const int q0 = qt * 128;
  const int li = lane & 15, lg = lane >> 4;
  const int li7 = li & 7;

  const int rowA = b*2048 + q0 + wid*32 + li;      // lane's q-row, group A
  const int rowB = rowA + 16;                      // group B

  // Q fragments for both q-groups (Wq carries 0.125*log2e -> log2 domain)
  bf16x8 qfA[2], qfB[2];
  {
    const unsigned short* qa = Q + (size_t)rowA*1024 + h*64 + lg*8;
    const unsigned short* qb = Q + (size_t)rowB*1024 + h*64 + lg*8;
    qfA[0] = *(const bf16x8*)qa; qfA[1] = *(const bf16x8*)(qa + 32);
    qfB[0] = *(const bf16x8*)qb; qfB[1] = *(const bf16x8*)(qb + 32);
  }

  f32x4 oaccA[4] = {}, oaccB[4] = {};
  float lrowA = 0.f, lrowB = 0.f;

  const int srow = lane >> 3;
  const int sblk = (lane & 7) ^ srow;    // source-side swizzle for K/V staging

  // stage tile 0
  #pragma unroll
  for(int i=0;i<2;i++){
    int r = wid*16 + i*8 + srow;
    glds16(K  + (size_t)(b*2048 + r)*1024 + h*64 + sblk*8, &Ksm[0][(wid*16 + i*8)*64]);
    glds16(Vt + (size_t)(bh*64 + r)*2048 + sblk*8,         &Vsm[0][(wid*16 + i*8)*64]);
  }
  uint2 mwA = *(const uint2*)&mp[(size_t)rowA*64];
  uint2 mwB = *(const uint2*)&mp[(size_t)rowB*64];
  uint2 mwAn, mwBn;
  __syncthreads();

  int buf = 0;
  for(int t = 0; t < 32; ++t){
    const int kv0 = t * 64;
    if(t < 31){
      #pragma unroll
      for(int i=0;i<2;i++){
        int r = wid*16 + i*8 + srow;
        glds16(K  + (size_t)(b*2048 + kv0 + 64 + r)*1024 + h*64 + sblk*8, &Ksm[buf^1][(wid*16 + i*8)*64]);
        glds16(Vt + (size_t)(bh*64 + r)*2048 + kv0 + 64 + sblk*8,         &Vsm[buf^1][(wid*16 + i*8)*64]);
      }
      mwAn = *(const uint2*)&mp[(size_t)rowA*64 + (size_t)((kv0 + 64) >> 5)];
      mwBn = *(const uint2*)&mp[(size_t)rowB*64 + (size_t)((kv0 + 64) >> 5)];
    }
    // S^T tiles for both q-groups: pX[f][j] = S[q][k=f*16+lg*4+j] (log2 domain)
    f32x4 pA[4], pB[4];
    __builtin_amdgcn_s_setprio(1);
    #pragma unroll
    for(int f=0; f<4; f++){
      f32x4 sa = {0.f,0.f,0.f,0.f}, sb = {0.f,0.f,0.f,0.f};
      #pragma unroll
      for(int kf=0; kf<2; kf++){
        int blk = (kf*4 + lg) ^ li7;
        bf16x8 kfr = *(const bf16x8*)&Ksm[buf][(f*16 + li)*64 + blk*8];
        sa = mfma16(kfr, qfA[kf], sa);
        sb = mfma16(kfr, qfB[kf], sb);
      }
      pA[f] = sa; pB[f] = sb;
    }
    __builtin_amdgcn_s_setprio(0);
    // fused softmax + PV, per k-16 subtile f: P stays lane-local (A-frag of 16x16x16)
    #pragma unroll
    for(int f=0; f<4; f++){
      unsigned int wA = (f < 2) ? mwA.x : mwA.y;
      unsigned int wB = (f < 2) ? mwB.x : mwB.y;
      float eA[4], eB[4];
      #pragma unroll
      for(int j=0;j<4;j++){
        unsigned int bitA = (wA >> ((f & 1)*16 + lg*4 + j)) & 1u;
        unsigned int bitB = (wB >> ((f & 1)*16 + lg*4 + j)) & 1u;
        float vA = exp2v(pA[f][j]);
        float vB = exp2v(pB[f][j]);
        eA[j] = bitA ? 0.f : vA;
        eB[j] = bitB ? 0.f : vB;
      }
      lrowA += (eA[0] + eA[1]) + (eA[2] + eA[3]);
      lrowB += (eB[0] + eB[1]) + (eB[2] + eB[3]);
      union { f16x2 h2[2]; f16x4 v; } ua, ub;
      ua.h2[0] = pkrtz(eA[0], eA[1]);
      ua.h2[1] = pkrtz(eA[2], eA[3]);
      ub.h2[0] = pkrtz(eB[0], eB[1]);
      ub.h2[1] = pkrtz(eB[2], eB[3]);
      const int blk = (f*2 + (lg >> 1)) ^ li7;
      const int sub = (lg & 1)*4;
      __builtin_amdgcn_s_setprio(1);
      #pragma unroll
      for(int dt=0; dt<4; dt++){
        f16x4 vf = *(const f16x4*)&Vsm[buf][(dt*16 + li)*64 + blk*8 + sub];
        oaccA[dt] = mfma16h(ua.v, vf, oaccA[dt]);
        oaccB[dt] = mfma16h(ub.v, vf, oaccB[dt]);
      }
      __builtin_amdgcn_s_setprio(0);
    }
    __syncthreads();
    mwA = mwAn; mwB = mwBn;
    buf ^= 1;
  }
  // reduce lane-partial sums (lanes sharing li), normalize, store both groups
  float rsA = lrowA, rsB = lrowB;
  rsA += __shfl_xor(rsA, 16); rsA += __shfl_xor(rsA, 32);
  rsB += __shfl_xor(rsB, 16); rsB += __shfl_xor(rsB, 32);
  float invA = 1.0f / rsA;               // valid for q-row (group A, index li)
  float invB = 1.0f / rsB;
  #pragma unroll
  for(int r=0;r<4;r++){
    float ioA = __shfl(invA, lg*4 + r);
    float ioB = __shfl(invB, lg*4 + r);
    size_t rbA = (size_t)(b*2048 + q0 + wid*32 + lg*4 + r);
    size_t rbB = rbA + 16;
    #pragma unroll
    for(int dt=0; dt<4; dt++){
      O[rbA*1024 + h*64 + 16*dt + li] = f2bf(oaccA[dt][r] * ioA);
      O[rbB*1024 + h*64 + 16*dt + li] = f2bf(oaccB[dt][r] * ioB);
    }
  }
}

// ---------- launch ----------
extern "C" void kernel_launch(void* const* d_in, const int* in_sizes, int n_in,
                              void* d_out, int out_size, void* d_ws, size_t ws_size,
                              hipStream_t stream)
{
  const float* q_in = (const float*)d_in[0];
  const float* k_in = (const float*)d_in[1];
  const float* v_in = (const float*)d_in[2];
  const unsigned char* mask = (const unsigned char*)d_in[3];
  const float* Wq = (const float*)d_in[4];
  const float* Wk = (const float*)d_in[5];
  const float* Wv = (const float*)d_in[6];
  const float* Wo = (const float*)d_in[7];

  char* ws = (char*)d_ws;
  const size_t MB = 1024*1024;
  int* flag          = (int*)ws;                              // 256 B
  unsigned short* XQ = (unsigned short*)(ws + 256);           // 8 MB
  unsigned short* XK = (unsigned short*)(ws + 256 + 8*MB);    // 8 MB
  unsigned short* XV = (unsigned short*)(ws + 256 + 16*MB);   // 8 MB
  unsigned short* WT = (unsigned short*)(ws + 256 + 24*MB);   // 8 MB (4 matrices)
  unsigned short* Qb = (unsigned short*)(ws + 256 + 32*MB);   // 8 MB
  unsigned short* Kb = (unsigned short*)(ws + 256 + 40*MB);   // 8 MB
  unsigned short* Vt = (unsigned short*)(ws + 256 + 48*MB);   // 8 MB (f16, transposed, direct from GEMM)
  unsigned short* Ob = XQ;                                    // attention output
  unsigned int*   mpk= (unsigned int*)XV;                     // packed mask (2 MB, written after GEMM reads XV)

  detect_kernel<<<1, 256, 0, stream>>>((const unsigned int*)mask, flag);
  cvt3_kernel<<<dim3(2048,3), 256, 0, stream>>>(q_in, k_in, v_in, XQ);
  transW_kernel<<<dim3(256,4), 256, 0, stream>>>(Wq, Wk, Wv, Wo, WT);
  gemm_bt<0><<<dim3(32,8,3), 256, 0, stream>>>(XQ, XK, XV,
                                               WT, WT + 1048576, WT + 2097152,
                                               Qb, Kb, Vt, nullptr);
  pack_mask_kernel<<<1024, 256, 0, stream>>>(mask, mpk, flag);
  attn_kernel<<<512, 256, 0, stream>>>(Qb, Kb, Vt, Ob, mpk);
  gemm_bt<1><<<dim3(32,8,1), 256, 0, stream>>>(Ob, Ob, Ob,
                                               WT + 3*1048576, WT + 3*1048576, WT + 3*1048576,
                                               nullptr, nullptr, nullptr, (float*)d_out);
}